// Round 3
// baseline (5669.604 us; speedup 1.0000x reference)
//
#include <hip/hip_runtime.h>
#include <hip/hip_bf16.h>
#include <cstdint>

// ---------------------------------------------------------------------------
// LSTM  B=64 T=512 I=512 H=512
// Phase 0: convert/transpose inputs -> bf16, W_cat^T bf16, b_cat f32,
//          U pre-swizzled into MFMA B-fragment order.
// Phase 1: x_proj GEMM [32768,512]@[512,2048] bf16 MFMA, bias folded in.
// Phase 2: persistent recurrence: 64 WGs = 4 batch-groups x 16 hidden-slices.
//          U slice in registers. h exchanged via TAGGED u64 words (hi32 = step
//          tag, lo32 = packed bf16 pair) with relaxed agent atomics: the data
//          IS the flag. No threadfence, no flag array, one barrier per step.
// Column convention: c = h_unit*4 + gate   (gate: 0=i,1=f,2=o,3=c)
// ---------------------------------------------------------------------------

typedef __bf16 bf16;
typedef __bf16 bf16x8 __attribute__((ext_vector_type(8)));
typedef float floatx4 __attribute__((ext_vector_type(4)));
typedef uint64_t u64;

#define T_STEPS 512

// ws layout (bytes)
#define XP_OFF     0ull                        // bf16 [T*B][2048]  = 128 MB
#define XBF_OFF    134217728ull                // bf16 [T*B][512]   = 32 MB
#define WCT_OFF    167772160ull                // bf16 [2048][512]  = 2 MB
#define USW_OFF    169869312ull                // bf16 swizzled U B-frags = 2 MB
#define BCAT_OFF   171966464ull                // f32  [2048]
#define HBUF_OFF   171974656ull                // u64 [2][4][16][256] = 256 KB

__device__ inline uint32_t pack_bf16x2(float a, float b) {
    union { __bf16 h[2]; uint32_t u; } cv;
    cv.h[0] = (__bf16)a; cv.h[1] = (__bf16)b;
    return cv.u;
}

// ---------------- K0a: inputs f32 [B][T][I] -> x_bf bf16 in row order (t*64+b)
__global__ void k0a_convert(const float* __restrict__ in, bf16* __restrict__ xbf) {
    int o = blockIdx.x * 256 + threadIdx.x;
    int k = o & 511;
    int r = o >> 9;
    int t = r >> 6, b = r & 63;
    xbf[o] = (bf16)in[(b * 512 + t) * 512 + k];
}

// ---------------- K0b: W_cat^T[c][k] bf16 (c = h*4+gate) and b_cat f32
__global__ void k0b_wcat(const float* __restrict__ Wi, const float* __restrict__ Wf,
                         const float* __restrict__ Wo, const float* __restrict__ Wc,
                         const float* __restrict__ bi, const float* __restrict__ bfv,
                         const float* __restrict__ bo, const float* __restrict__ bc,
                         bf16* __restrict__ wct, float* __restrict__ bcat) {
    int o = blockIdx.x * 256 + threadIdx.x;      // o = c*512 + k
    int k = o & 511;
    int c = o >> 9;
    int h = c >> 2, g = c & 3;
    const float* W = (g == 0) ? Wi : (g == 1) ? Wf : (g == 2) ? Wo : Wc;
    wct[o] = (bf16)W[k * 512 + h];
    if (o < 2048) {
        int hh = o >> 2, gg = o & 3;
        const float* bv = (gg == 0) ? bi : (gg == 1) ? bfv : (gg == 2) ? bo : bc;
        bcat[o] = bv[hh];
    }
}

// ---------------- K0c: U pre-swizzled into B-fragment order for phase 2.
__global__ void k0c_uswz(const float* __restrict__ Ui, const float* __restrict__ Uf,
                         const float* __restrict__ Uo, const float* __restrict__ Uc,
                         bf16* __restrict__ usw) {
    int o = blockIdx.x * 256 + threadIdx.x;      // [0, 1048576)
    int e  = o & 7;
    int l  = (o >> 3) & 63;
    int ks = (o >> 9) & 15;
    int nt = (o >> 13) & 1;
    int w  = (o >> 14) & 3;
    int s  = o >> 16;
    int k = ks * 32 + (l >> 4) * 8 + e;
    int col_local = (2 * w + nt) * 16 + (l & 15);
    int h = s * 32 + (col_local >> 2);
    int g = col_local & 3;
    const float* U = (g == 0) ? Ui : (g == 1) ? Uf : (g == 2) ? Uo : Uc;
    usw[o] = (bf16)U[k * 512 + h];
}

// ---------------- K1: xp = x_bf @ W_cat + b_cat   (bf16 out)
__launch_bounds__(256, 2)
__global__ void k1_gemm(const bf16* __restrict__ xbf, const bf16* __restrict__ wct,
                        const float* __restrict__ bcat, bf16* __restrict__ xp) {
    __shared__ bf16 As[128 * 40];
    __shared__ bf16 Bs[128 * 40];
    int tid = threadIdx.x;
    int wid = tid >> 6, lane = tid & 63;
    int q = lane >> 4, m = lane & 15;
    int wr = wid >> 1, wc = wid & 1;
    int br = blockIdx.x & 255, bc = blockIdx.x >> 8;

    floatx4 acc[4][4] = {};

    for (int kk = 0; kk < 16; ++kk) {
        #pragma unroll
        for (int cc = 0; cc < 2; ++cc) {
            int ch = tid + cc * 256;
            int row = ch >> 2, part = ch & 3;
            bf16x8 va = *(const bf16x8*)&xbf[(br * 128 + row) * 512 + kk * 32 + part * 8];
            bf16x8 vb = *(const bf16x8*)&wct[(bc * 128 + row) * 512 + kk * 32 + part * 8];
            *(bf16x8*)&As[row * 40 + part * 8] = va;
            *(bf16x8*)&Bs[row * 40 + part * 8] = vb;
        }
        __syncthreads();
        bf16x8 af[4], bfr[4];
        #pragma unroll
        for (int i = 0; i < 4; ++i) {
            af[i]  = *(const bf16x8*)&As[(wr * 64 + i * 16 + m) * 40 + q * 8];
            bfr[i] = *(const bf16x8*)&Bs[(wc * 64 + i * 16 + m) * 40 + q * 8];
        }
        #pragma unroll
        for (int mt = 0; mt < 4; ++mt)
            #pragma unroll
            for (int nt = 0; nt < 4; ++nt)
                acc[mt][nt] = __builtin_amdgcn_mfma_f32_16x16x32_bf16(
                    af[mt], bfr[nt], acc[mt][nt], 0, 0, 0);
        __syncthreads();
    }
    #pragma unroll
    for (int nt = 0; nt < 4; ++nt) {
        int C = bc * 128 + wc * 64 + nt * 16 + m;
        float bias = bcat[C];
        #pragma unroll
        for (int mt = 0; mt < 4; ++mt) {
            #pragma unroll
            for (int r = 0; r < 4; ++r) {
                int R = br * 128 + wr * 64 + mt * 16 + q * 4 + r;
                xp[(long)R * 2048 + C] = (bf16)(acc[mt][nt][r] + bias);
            }
        }
    }
}

// ---------------- K2: persistent recurrence (tagged-word protocol).
// 64 blocks x 256 threads. block = (bg = blockIdx&3, s = blockIdx>>2).
// hbuf: u64[2][4][16][256]; word j of row r: hi32 = tag (t+1), lo32 = packed
// bf16 pair (h[2j], h[2j+1]). Store parity = t&1; read parity = (t-1)&1.
// Safety: the per-step __syncthreads (g_lds) orders every WG's h-reads before
// its h-store, so parity-p words are never overwritten while still needed.
__launch_bounds__(256, 1)
__global__ void k2_rec(const bf16* __restrict__ xp, const bf16* __restrict__ usw,
                       u64* __restrict__ hbuf, float* __restrict__ out) {
    __shared__ float g_lds[2][128 * 21];          // parity, [col_local][row] pad 16->21

    int tid = threadIdx.x;
    int wid = tid >> 6, lane = tid & 63;
    int q = lane >> 4, m = lane & 15;
    int bg = blockIdx.x & 3, s = blockIdx.x >> 2;

    // U B-fragments in registers (one-time, reused all 512 steps)
    bf16x8 bfr[2][16];
    {
        const bf16x8* base = (const bf16x8*)usw;
        #pragma unroll
        for (int nt = 0; nt < 2; ++nt)
            #pragma unroll
            for (int ks = 0; ks < 16; ++ks)
                bfr[nt][ks] = base[(((s * 4 + wid) * 2 + nt) * 16 + ks) * 64 + lane];
    }

    // gate-thread mapping: batch row r (0..15), hidden cols jc, jc+1
    int r = tid >> 4;
    int jc = (tid & 15) * 2;
    float cs0 = 0.f, cs1 = 0.f;

    // producer store address: word j = s*16 + (tid&15), row r
    u64* my_word_base = hbuf + ((size_t)bg * 16 + r) * 256 + s * 16 + (tid & 15);

    for (int t = 0; t < T_STEPS; ++t) {
        // xp prefetch (C-frag layout), independent of h — overlaps everything
        float xpv[2][4];
        #pragma unroll
        for (int nt = 0; nt < 2; ++nt) {
            int Cg = s * 128 + (2 * wid + nt) * 16 + m;
            #pragma unroll
            for (int rr = 0; rr < 4; ++rr) {
                int R = t * 64 + bg * 16 + q * 4 + rr;
                xpv[nt][rr] = (float)xp[(long)R * 2048 + Cg];
            }
        }
        floatx4 acc[2];
        #pragma unroll
        for (int nt = 0; nt < 2; ++nt) {
            acc[nt][0] = xpv[nt][0]; acc[nt][1] = xpv[nt][1];
            acc[nt][2] = xpv[nt][2]; acc[nt][3] = xpv[nt][3];
        }

        if (t > 0) {
            uint32_t tg = (uint32_t)t;              // tag of h_{t-1}
            const u64* rb = hbuf + ((((size_t)((t - 1) & 1) * 4 + bg) * 16) + m) * 256;
            // bulk-issue all 64 tagged loads (A-frag ks: words ks*16+q*4+{0..3})
            u64 w[64];
            #pragma unroll
            for (int ks = 0; ks < 16; ++ks)
                #pragma unroll
                for (int i = 0; i < 4; ++i)
                    w[ks * 4 + i] = __hip_atomic_load(rb + ks * 16 + q * 4 + i,
                                                      __ATOMIC_RELAXED,
                                                      __HIP_MEMORY_SCOPE_AGENT);
            // poll: predicated reload of stale words only
            while (true) {
                bool ok = true;
                #pragma unroll
                for (int x = 0; x < 64; ++x) ok &= ((uint32_t)(w[x] >> 32) == tg);
                if (__all((int)ok)) break;
                __builtin_amdgcn_s_sleep(1);
                #pragma unroll
                for (int ks = 0; ks < 16; ++ks)
                    #pragma unroll
                    for (int i = 0; i < 4; ++i)
                        if ((uint32_t)(w[ks * 4 + i] >> 32) != tg)
                            w[ks * 4 + i] = __hip_atomic_load(rb + ks * 16 + q * 4 + i,
                                                              __ATOMIC_RELAXED,
                                                              __HIP_MEMORY_SCOPE_AGENT);
            }
            // MFMA: g += h_{t-1} @ U_slice
            #pragma unroll
            for (int ks = 0; ks < 16; ++ks) {
                union { uint32_t u[4]; bf16x8 v; } cv;
                cv.u[0] = (uint32_t)w[ks * 4 + 0];
                cv.u[1] = (uint32_t)w[ks * 4 + 1];
                cv.u[2] = (uint32_t)w[ks * 4 + 2];
                cv.u[3] = (uint32_t)w[ks * 4 + 3];
                acc[0] = __builtin_amdgcn_mfma_f32_16x16x32_bf16(cv.v, bfr[0][ks], acc[0], 0, 0, 0);
                acc[1] = __builtin_amdgcn_mfma_f32_16x16x32_bf16(cv.v, bfr[1][ks], acc[1], 0, 0, 0);
            }
        }

        // scatter g to parity LDS: g_lds[t&1][col_local][row]
        float* gl = g_lds[t & 1];
        #pragma unroll
        for (int nt = 0; nt < 2; ++nt) {
            int col = (2 * wid + nt) * 16 + m;
            *(floatx4*)&gl[col * 21 + q * 4] = acc[nt];
        }
        __syncthreads();   // ONLY barrier per step (also orders h-reads < h-store)

        // gates: thread handles units (r, jc) and (r, jc+1)
        float h0, h1;
        {
            float gi = gl[(jc * 4 + 0) * 21 + r];
            float gf = gl[(jc * 4 + 1) * 21 + r];
            float go = gl[(jc * 4 + 2) * 21 + r];
            float gc = gl[(jc * 4 + 3) * 21 + r];
            float ig = 1.f / (1.f + __expf(-gi));
            float fg = 1.f / (1.f + __expf(-gf));
            float og = 1.f / (1.f + __expf(-go));
            float th = 1.f - 2.f / (__expf(2.f * gc) + 1.f);
            cs0 = fg * cs0 + ig * th;
            h0 = og * (1.f - 2.f / (__expf(2.f * cs0) + 1.f));
        }
        {
            float gi = gl[((jc + 1) * 4 + 0) * 21 + r];
            float gf = gl[((jc + 1) * 4 + 1) * 21 + r];
            float go = gl[((jc + 1) * 4 + 2) * 21 + r];
            float gc = gl[((jc + 1) * 4 + 3) * 21 + r];
            float ig = 1.f / (1.f + __expf(-gi));
            float fg = 1.f / (1.f + __expf(-gf));
            float og = 1.f / (1.f + __expf(-go));
            float th = 1.f - 2.f / (__expf(2.f * gc) + 1.f);
            cs1 = fg * cs1 + ig * th;
            h1 = og * (1.f - 2.f / (__expf(2.f * cs1) + 1.f));
        }
        // tagged publish: hi32 = t+1, lo32 = packed pair. Parity t&1.
        u64 word = ((u64)(uint32_t)(t + 1) << 32) | (u64)pack_bf16x2(h0, h1);
        __hip_atomic_store(my_word_base + ((size_t)(t & 1) * 4 * 16 * 256), word,
                           __ATOMIC_RELAXED, __HIP_MEMORY_SCOPE_AGENT);
        if (t == T_STEPS - 1) {
            out[(bg * 16 + r) * 512 + s * 32 + jc]     = h0;
            out[(bg * 16 + r) * 512 + s * 32 + jc + 1] = h1;
        }
    }
}

// ---------------------------------------------------------------------------
extern "C" void kernel_launch(void* const* d_in, const int* in_sizes, int n_in,
                              void* d_out, int out_size, void* d_ws, size_t ws_size,
                              hipStream_t stream) {
    const float* inp = (const float*)d_in[0];
    const float* Wi  = (const float*)d_in[1];
    const float* Wf  = (const float*)d_in[2];
    const float* Wo  = (const float*)d_in[3];
    const float* Wc  = (const float*)d_in[4];
    const float* Ui  = (const float*)d_in[5];
    const float* Uf  = (const float*)d_in[6];
    const float* Uo  = (const float*)d_in[7];
    const float* Uc  = (const float*)d_in[8];
    const float* bi  = (const float*)d_in[9];
    const float* bfv = (const float*)d_in[10];
    const float* bo  = (const float*)d_in[11];
    const float* bc  = (const float*)d_in[12];

    char* ws = (char*)d_ws;
    bf16*  xp    = (bf16*)(ws + XP_OFF);
    bf16*  xbf   = (bf16*)(ws + XBF_OFF);
    bf16*  wct   = (bf16*)(ws + WCT_OFF);
    bf16*  usw   = (bf16*)(ws + USW_OFF);
    float* bcat  = (float*)(ws + BCAT_OFF);
    u64*   hbuf  = (u64*)(ws + HBUF_OFF);

    k0a_convert<<<65536, 256, 0, stream>>>(inp, xbf);
    k0b_wcat<<<4096, 256, 0, stream>>>(Wi, Wf, Wo, Wc, bi, bfv, bo, bc, wct, bcat);
    k0c_uswz<<<4096, 256, 0, stream>>>(Ui, Uf, Uo, Uc, usw);
    k1_gemm<<<4096, 256, 0, stream>>>(xbf, wct, bcat, xp);
    k2_rec<<<64, 256, 0, stream>>>(xp, usw, hbuf, (float*)d_out);
}

// Round 4
// 1456.195 us; speedup vs baseline: 3.8934x; 3.8934x over previous
//
#include <hip/hip_runtime.h>
#include <hip/hip_bf16.h>
#include <cstdint>

// ---------------------------------------------------------------------------
// LSTM  B=64 T=512 I=512 H=512
// Phase 0: convert/transpose inputs -> bf16, W_cat^T bf16, b_cat f32,
//          U pre-swizzled into MFMA B-fragment order.
// Phase 1: x_proj GEMM bf16 MFMA, bias folded, output in CONSUMER-SWIZZLED
//          order (k2's per-thread xp read = one coalesced 8B load per nt).
// Phase 2: persistent recurrence: 64 WGs = 4 batch-groups x 16 hidden-slices.
//          U slice in registers. h exchanged via TAGGED u64 words (hi32 = tag
//          t+1, lo32 = packed bf16 pair), relaxed agent atomics: data IS the
//          flag — producer chain is gates -> tagged store (no barrier/ack/flag
//          hop). Consumer: coalesced bulk load of 16 words/thread + cheap tag
//          check + flat reload on staleness; fresh pairs staged via LDS.
// Safety: two __syncthreads per step order all of a WG's h-reads before its
// h-store; a WG stores tag t+2 only after observing all tag t+1 words, which
// producers publish only after completing their tag-t reads => the parity
// block a step-t reader uses is never clobbered early.
// Column convention: c = h_unit*4 + gate   (gate: 0=i,1=f,2=o,3=c)
// ---------------------------------------------------------------------------

typedef __bf16 bf16;
typedef __bf16 bf16x8 __attribute__((ext_vector_type(8)));
typedef float floatx4 __attribute__((ext_vector_type(4)));
typedef uint64_t u64;
typedef uint32_t u32;

#define T_STEPS 512

// ws layout (bytes)
#define XP_OFF     0ull                        // bf16 [T*B*2048] swizzled = 128 MB
#define XBF_OFF    134217728ull                // bf16 [T*B][512]   = 32 MB
#define WCT_OFF    167772160ull                // bf16 [2048][512]  = 2 MB
#define USW_OFF    169869312ull                // bf16 swizzled U B-frags = 2 MB
#define BCAT_OFF   171966464ull                // f32  [2048]
#define HBUF_OFF   171974656ull                // u64 [2][4][16][256] = 256 KB

__device__ inline u32 pack_bf16x2(float a, float b) {
    union { __bf16 h[2]; u32 u; } cv;
    cv.h[0] = (__bf16)a; cv.h[1] = (__bf16)b;
    return cv.u;
}

// ---------------- K0a: inputs f32 [B][T][I] -> x_bf bf16 in row order (t*64+b)
__global__ void k0a_convert(const float* __restrict__ in, bf16* __restrict__ xbf) {
    int o = blockIdx.x * 256 + threadIdx.x;
    int k = o & 511;
    int r = o >> 9;
    int t = r >> 6, b = r & 63;
    xbf[o] = (bf16)in[(b * 512 + t) * 512 + k];
}

// ---------------- K0b: W_cat^T[c][k] bf16 (c = h*4+gate) and b_cat f32
__global__ void k0b_wcat(const float* __restrict__ Wi, const float* __restrict__ Wf,
                         const float* __restrict__ Wo, const float* __restrict__ Wc,
                         const float* __restrict__ bi, const float* __restrict__ bfv,
                         const float* __restrict__ bo, const float* __restrict__ bc,
                         bf16* __restrict__ wct, float* __restrict__ bcat) {
    int o = blockIdx.x * 256 + threadIdx.x;      // o = c*512 + k
    int k = o & 511;
    int c = o >> 9;
    int h = c >> 2, g = c & 3;
    const float* W = (g == 0) ? Wi : (g == 1) ? Wf : (g == 2) ? Wo : Wc;
    wct[o] = (bf16)W[k * 512 + h];
    if (o < 2048) {
        int hh = o >> 2, gg = o & 3;
        const float* bv = (gg == 0) ? bi : (gg == 1) ? bfv : (gg == 2) ? bo : bc;
        bcat[o] = bv[hh];
    }
}

// ---------------- K0c: U pre-swizzled into B-fragment order for phase 2.
__global__ void k0c_uswz(const float* __restrict__ Ui, const float* __restrict__ Uf,
                         const float* __restrict__ Uo, const float* __restrict__ Uc,
                         bf16* __restrict__ usw) {
    int o = blockIdx.x * 256 + threadIdx.x;      // [0, 1048576)
    int e  = o & 7;
    int l  = (o >> 3) & 63;
    int ks = (o >> 9) & 15;
    int nt = (o >> 13) & 1;
    int w  = (o >> 14) & 3;
    int s  = o >> 16;
    int k = ks * 32 + (l >> 4) * 8 + e;
    int col_local = (2 * w + nt) * 16 + (l & 15);
    int h = s * 32 + (col_local >> 2);
    int g = col_local & 3;
    const float* U = (g == 0) ? Ui : (g == 1) ? Uf : (g == 2) ? Uo : Uc;
    usw[o] = (bf16)U[k * 512 + h];
}

// ---------------- K1: xp = x_bf @ W_cat + b_cat, output SWIZZLED for k2.
// Swizzle: value at (R = t*64 + bg*16 + q*4 + rr, C = s*128 + widc*16 + m)
// lands at flat bf16 index ((((t*4+bg)*16+s)*8+widc)*64 + q*16+m)*4 + rr.
__launch_bounds__(256, 2)
__global__ void k1_gemm(const bf16* __restrict__ xbf, const bf16* __restrict__ wct,
                        const float* __restrict__ bcat, bf16* __restrict__ xp) {
    __shared__ bf16 As[128 * 40];
    __shared__ bf16 Bs[128 * 40];
    int tid = threadIdx.x;
    int wid = tid >> 6, lane = tid & 63;
    int q = lane >> 4, m = lane & 15;
    int wr = wid >> 1, wc = wid & 1;
    int br = blockIdx.x & 255, bc = blockIdx.x >> 8;

    floatx4 acc[4][4] = {};

    for (int kk = 0; kk < 16; ++kk) {
        #pragma unroll
        for (int cc = 0; cc < 2; ++cc) {
            int ch = tid + cc * 256;
            int row = ch >> 2, part = ch & 3;
            bf16x8 va = *(const bf16x8*)&xbf[(br * 128 + row) * 512 + kk * 32 + part * 8];
            bf16x8 vb = *(const bf16x8*)&wct[(bc * 128 + row) * 512 + kk * 32 + part * 8];
            *(bf16x8*)&As[row * 40 + part * 8] = va;
            *(bf16x8*)&Bs[row * 40 + part * 8] = vb;
        }
        __syncthreads();
        bf16x8 af[4], bfr[4];
        #pragma unroll
        for (int i = 0; i < 4; ++i) {
            af[i]  = *(const bf16x8*)&As[(wr * 64 + i * 16 + m) * 40 + q * 8];
            bfr[i] = *(const bf16x8*)&Bs[(wc * 64 + i * 16 + m) * 40 + q * 8];
        }
        #pragma unroll
        for (int mt = 0; mt < 4; ++mt)
            #pragma unroll
            for (int nt = 0; nt < 4; ++nt)
                acc[mt][nt] = __builtin_amdgcn_mfma_f32_16x16x32_bf16(
                    af[mt], bfr[nt], acc[mt][nt], 0, 0, 0);
        __syncthreads();
    }
    // epilogue: +bias, pack 4 bf16 (rr=0..3) per (mt,nt2), coalesced 8B stores.
    // t = br*2+wr, bg = mt, s = bc, widc = wc*4+nt2, lane index = lane.
    float bias[4];
    #pragma unroll
    for (int nt = 0; nt < 4; ++nt) bias[nt] = bcat[bc * 128 + wc * 64 + nt * 16 + m];
    #pragma unroll
    for (int mt = 0; mt < 4; ++mt) {
        #pragma unroll
        for (int nt = 0; nt < 4; ++nt) {
            u32 p0 = pack_bf16x2(acc[mt][nt][0] + bias[nt], acc[mt][nt][1] + bias[nt]);
            u32 p1 = pack_bf16x2(acc[mt][nt][2] + bias[nt], acc[mt][nt][3] + bias[nt]);
            size_t idx = (((((size_t)(br * 2 + wr) * 4 + mt) * 16 + bc) * 8
                           + wc * 4 + nt) * 64 + lane) * 4;
            uint2 v; v.x = p0; v.y = p1;
            *(uint2*)&xp[idx] = v;
        }
    }
}

// ---------------- K2: persistent recurrence (tagged words, coalesced consumer)
// hbuf: u64[2][4][16][256]; word (par,bg,row,pc): hi32 = tag t+1, lo32 = packed
// bf16 pair (h[2pc], h[2pc+1]). Store parity t&1, read parity (t-1)&1.
__launch_bounds__(256, 1)
__global__ void k2_rec(const bf16* __restrict__ xp, const bf16* __restrict__ usw,
                       u64* __restrict__ hbuf, float* __restrict__ out) {
    __shared__ bf16 h_lds[16 * 520];              // rows padded 512->520
    __shared__ float g_lds[2][128 * 21];          // parity, [col_local][row]
    u32* h32 = (u32*)h_lds;

    int tid = threadIdx.x;
    int wid = tid >> 6, lane = tid & 63;
    int q = lane >> 4, m = lane & 15;
    int bg = blockIdx.x & 3, s = blockIdx.x >> 2;

    // U B-fragments in registers (one-time, reused all 512 steps)
    bf16x8 bfr[2][16];
    {
        const bf16x8* base = (const bf16x8*)usw;
        #pragma unroll
        for (int nt = 0; nt < 2; ++nt)
            #pragma unroll
            for (int ks = 0; ks < 16; ++ks)
                bfr[nt][ks] = base[(((s * 4 + wid) * 2 + nt) * 16 + ks) * 64 + lane];
    }

    // gate-thread mapping: batch row r (0..15), local hidden cols jc, jc+1
    int r = tid >> 4;
    int jc = (tid & 15) * 2;
    float cs0 = 0.f, cs1 = 0.f;

    for (int t = 0; t < T_STEPS; ++t) {
        // xp (pre-swizzled): two coalesced 8B loads -> acc init (C-frag order)
        floatx4 acc[2];
        #pragma unroll
        for (int nt = 0; nt < 2; ++nt) {
            size_t idx = (((((size_t)t * 4 + bg) * 16 + s) * 8 + wid * 2 + nt) * 64 + lane) * 4;
            uint2 v = *(const uint2*)&xp[idx];
            acc[nt][0] = __builtin_bit_cast(float, v.x << 16);
            acc[nt][1] = __builtin_bit_cast(float, v.x & 0xffff0000u);
            acc[nt][2] = __builtin_bit_cast(float, v.y << 16);
            acc[nt][3] = __builtin_bit_cast(float, v.y & 0xffff0000u);
        }

        if (t > 0) {
            const u64* rb = hbuf + ((size_t)((t - 1) & 1) * 4 + bg) * 4096;
            u32 tg = (u32)t;
            // coalesced bulk load: thread covers words tid + 256*i (row i, pair tid)
            u64 w[16];
            #pragma unroll
            for (int i = 0; i < 16; ++i)
                w[i] = __hip_atomic_load(rb + tid + 256 * i, __ATOMIC_RELAXED,
                                         __HIP_MEMORY_SCOPE_AGENT);
            while (true) {
                bool ok = true;
                #pragma unroll
                for (int i = 0; i < 16; ++i) ok &= ((u32)(w[i] >> 32) == tg);
                if (ok) break;
                #pragma unroll
                for (int i = 0; i < 16; ++i)
                    w[i] = __hip_atomic_load(rb + tid + 256 * i, __ATOMIC_RELAXED,
                                             __HIP_MEMORY_SCOPE_AGENT);
            }
            // strip tags, stage pairs to LDS: row i, pair col tid
            #pragma unroll
            for (int i = 0; i < 16; ++i)
                h32[i * 260 + tid] = (u32)w[i];
            __syncthreads();                      // barrier A
            // A-frags from LDS, MFMA: g += h_{t-1} @ U_slice
            #pragma unroll
            for (int ks = 0; ks < 16; ++ks) {
                bf16x8 a = *(const bf16x8*)&h_lds[m * 520 + ks * 32 + q * 8];
                acc[0] = __builtin_amdgcn_mfma_f32_16x16x32_bf16(a, bfr[0][ks], acc[0], 0, 0, 0);
                acc[1] = __builtin_amdgcn_mfma_f32_16x16x32_bf16(a, bfr[1][ks], acc[1], 0, 0, 0);
            }
        }

        // scatter g to parity LDS: g_lds[t&1][col_local][row]
        float* gl = g_lds[t & 1];
        #pragma unroll
        for (int nt = 0; nt < 2; ++nt) {
            int col = (2 * wid + nt) * 16 + m;
            *(floatx4*)&gl[col * 21 + q * 4] = acc[nt];
        }
        __syncthreads();                          // barrier B

        // gates: thread handles units (r, jc) and (r, jc+1)
        float h0, h1;
        {
            float gi = gl[(jc * 4 + 0) * 21 + r];
            float gf = gl[(jc * 4 + 1) * 21 + r];
            float go = gl[(jc * 4 + 2) * 21 + r];
            float gc = gl[(jc * 4 + 3) * 21 + r];
            float ig = 1.f / (1.f + __expf(-gi));
            float fg = 1.f / (1.f + __expf(-gf));
            float og = 1.f / (1.f + __expf(-go));
            float th = 1.f - 2.f / (__expf(2.f * gc) + 1.f);
            cs0 = fg * cs0 + ig * th;
            h0 = og * (1.f - 2.f / (__expf(2.f * cs0) + 1.f));
        }
        {
            float gi = gl[((jc + 1) * 4 + 0) * 21 + r];
            float gf = gl[((jc + 1) * 4 + 1) * 21 + r];
            float go = gl[((jc + 1) * 4 + 2) * 21 + r];
            float gc = gl[((jc + 1) * 4 + 3) * 21 + r];
            float ig = 1.f / (1.f + __expf(-gi));
            float fg = 1.f / (1.f + __expf(-gf));
            float og = 1.f / (1.f + __expf(-go));
            float th = 1.f - 2.f / (__expf(2.f * gc) + 1.f);
            cs1 = fg * cs1 + ig * th;
            h1 = og * (1.f - 2.f / (__expf(2.f * cs1) + 1.f));
        }
        // tagged publish: hi32 = t+1, lo32 = packed pair. Parity t&1.
        u64 word = ((u64)(u32)(t + 1) << 32) | (u64)pack_bf16x2(h0, h1);
        __hip_atomic_store(hbuf + (((size_t)(t & 1) * 4 + bg) * 16 + r) * 256
                                + s * 16 + (tid & 15),
                           word, __ATOMIC_RELAXED, __HIP_MEMORY_SCOPE_AGENT);
        if (t == T_STEPS - 1) {
            out[(bg * 16 + r) * 512 + s * 32 + jc]     = h0;
            out[(bg * 16 + r) * 512 + s * 32 + jc + 1] = h1;
        }
    }
}

// ---------------------------------------------------------------------------
extern "C" void kernel_launch(void* const* d_in, const int* in_sizes, int n_in,
                              void* d_out, int out_size, void* d_ws, size_t ws_size,
                              hipStream_t stream) {
    const float* inp = (const float*)d_in[0];
    const float* Wi  = (const float*)d_in[1];
    const float* Wf  = (const float*)d_in[2];
    const float* Wo  = (const float*)d_in[3];
    const float* Wc  = (const float*)d_in[4];
    const float* Ui  = (const float*)d_in[5];
    const float* Uf  = (const float*)d_in[6];
    const float* Uo  = (const float*)d_in[7];
    const float* Uc  = (const float*)d_in[8];
    const float* bi  = (const float*)d_in[9];
    const float* bfv = (const float*)d_in[10];
    const float* bo  = (const float*)d_in[11];
    const float* bc  = (const float*)d_in[12];

    char* ws = (char*)d_ws;
    bf16*  xp    = (bf16*)(ws + XP_OFF);
    bf16*  xbf   = (bf16*)(ws + XBF_OFF);
    bf16*  wct   = (bf16*)(ws + WCT_OFF);
    bf16*  usw   = (bf16*)(ws + USW_OFF);
    float* bcat  = (float*)(ws + BCAT_OFF);
    u64*   hbuf  = (u64*)(ws + HBUF_OFF);

    k0a_convert<<<65536, 256, 0, stream>>>(inp, xbf);
    k0b_wcat<<<4096, 256, 0, stream>>>(Wi, Wf, Wo, Wc, bi, bfv, bo, bc, wct, bcat);
    k0c_uswz<<<4096, 256, 0, stream>>>(Ui, Uf, Uo, Uc, usw);
    k1_gemm<<<4096, 256, 0, stream>>>(xbf, wct, bcat, xp);
    k2_rec<<<64, 256, 0, stream>>>(xp, usw, hbuf, (float*)d_out);
}